// Round 6
// baseline (121.943 us; speedup 1.0000x reference)
//
#include <hip/hip_runtime.h>
#include <hip/hip_bf16.h>

typedef unsigned short u16;
typedef __bf16 bf16x8 __attribute__((ext_vector_type(8)));
typedef float f32x4 __attribute__((ext_vector_type(4)));
typedef u16 u16x4 __attribute__((ext_vector_type(4)));

#define B_ 2
#define L_ 2048
#define D_ 128
#define KLAY 3
#define NR 16
#define NATOM 118
#define DD (D_ * D_)
#define XTN (L_ * D_)
#define BLN (B_ * L_ * NR)

static __device__ __forceinline__ u16 f2bf(float f) {
    union { float f; unsigned u; } v; v.f = f;
    unsigned r = v.u + 0x7FFFu + ((v.u >> 16) & 1u);
    return (u16)(r >> 16);
}
static __device__ __forceinline__ bf16x8 ld_bf8(const u16* p) {
    return *(const bf16x8*)p;
}

// ---------------- prep: weights -> bf16 [n][k] layouts ----------------
__global__ __launch_bounds__(256) void prep_kernel(
    const float* atom_emb, const float* out_w, const float* self_w,
    const float* msg_w, const float* upd_w,
    u16* atom16, u16* outwT, u16* selfT, u16* msgT, u16* updT) {
    const int T0 = NATOM * D_;
    const int T1 = D_ * 2 * D_;
    const int T2 = KLAY * DD;
    const int T3 = KLAY * DD;
    const int T4 = KLAY * 2 * DD;
    int total = T0 + T1 + T2 + T3 + T4;
    for (int t = blockIdx.x * blockDim.x + threadIdx.x; t < total;
         t += gridDim.x * blockDim.x) {
        int u = t;
        if (u < T0) { atom16[u] = f2bf(atom_emb[u]); continue; }
        u -= T0;
        if (u < T1) {
            int n = u / (2 * D_), k = u % (2 * D_);
            outwT[u] = f2bf(out_w[k * D_ + n]);
            continue;
        }
        u -= T1;
        if (u < T2) {
            int kk = u / DD, v = u % DD;
            int n = v / D_, k = v % D_;
            selfT[u] = f2bf(self_w[kk * DD + k * D_ + n]);
            continue;
        }
        u -= T2;
        if (u < T3) {
            int kk = u / DD, v = u % DD;
            int n = v / D_, k = v % D_;
            msgT[u] = f2bf(msg_w[kk * DD + k * D_ + n]);
            continue;
        }
        u -= T3;
        {
            int kk = u / (2 * DD), v = u % (2 * DD);
            int n = v / (2 * D_), k = v % (2 * D_);
            updT[u] = f2bf(upd_w[kk * 2 * DD + k * D_ + n]);
        }
    }
}

// ---------------- pairw: W (MFMA A-frag layout) + RBF partial sums ----------------
// block = (rowtile rt, j-quarter jq). Wf[rt][sg][row][k], sg = j>>5 (64 slices).
// RBF via grouped-exp identity: exp(-g(d-c4g-m*dl)^2) = base_g * u_g^m * K_m
__global__ __launch_bounds__(512) void pairw_kernel(
    const float* coords, const float* gamma_p, const float* centers,
    u16* Wf, float* rbfp) {
    int bid = blockIdx.x;
    int rt = bid >> 2, jq = bid & 3;
    int gi0 = rt * 16;
    int b = gi0 >> 11;
    int t = threadIdx.x;
    int row = t >> 5, k = t & 31;
    int gi = gi0 + row;

    __shared__ float cj[512 * 3];  // 6 KB: this j-quarter's coords
    {
        const float4* src = (const float4*)(coords + ((size_t)b * L_ + jq * 512) * 3);
        float4* dst = (float4*)cj;
        if (t < 384) dst[t] = src[t];
    }
    float gamma = gamma_p[0];
    float dl = centers[1] - centers[0];
    float c4[4];
#pragma unroll
    for (int g = 0; g < 4; g++) c4[g] = centers[4 * g];
    float two_gdl = 2.f * gamma * dl;
    float cx = coords[gi * 3 + 0];
    float cy = coords[gi * 3 + 1];
    float cz = coords[gi * 3 + 2];
    __syncthreads();

    float acc[4][4];
#pragma unroll
    for (int g = 0; g < 4; g++)
#pragma unroll
        for (int m = 0; m < 4; m++) acc[g][m] = 0.f;

    u16* wbase = Wf + (size_t)rt * (64 * 512) + (jq * 16) * 512 + t;
#pragma unroll 4
    for (int s = 0; s < 16; s++) {
        int jl = s * 32 + k;
        float dx = cx - cj[jl * 3 + 0];
        float dy = cy - cj[jl * 3 + 1];
        float dz = cz - cj[jl * 3 + 2];
        float sq = dx * dx + dy * dy + dz * dz;
        float d = sqrtf(sq);  // sq==0 only for i==j; sqrt(0)=0 exact
        wbase[s * 512] = f2bf(__expf(-d));
#pragma unroll
        for (int g = 0; g < 4; g++) {
            float x = d - c4[g];
            float base = __expf(-gamma * x * x);
            float u = __expf(fminf(two_gdl * x, 29.f));
            float p = base;
            acc[g][0] += p;
            p *= u; acc[g][1] += p;
            p *= u; acc[g][2] += p;
            p *= u; acc[g][3] += p;
        }
    }
    // reduce across the row's 32 lanes (stay within 32-lane halves)
#pragma unroll
    for (int off = 16; off > 0; off >>= 1)
#pragma unroll
        for (int g = 0; g < 4; g++)
#pragma unroll
            for (int m = 0; m < 4; m++) acc[g][m] += __shfl_xor(acc[g][m], off);
    if (k == 0) {
#pragma unroll
        for (int m = 0; m < 4; m++) {
            float Km = __expf(-gamma * (m * dl) * (m * dl)) * (1.0f / L_);
#pragma unroll
            for (int g = 0; g < 4; g++)
                rbfp[(size_t)jq * BLN + (size_t)gi * NR + 4 * g + m] = acc[g][m] * Km;
        }
    }
}

// ---------------- enc_sx: encoder + layer-0 S/X (row-local) ----------------
__global__ __launch_bounds__(256) void enc_sx_kernel(
    const int* Z, const float* rbf_w, const float* rbf_b, const float* out_b,
    const float* rbfp, const u16* atom16, const u16* outwT,
    const u16* selfT0, const u16* msgT0, const float* self_b0, const float* msg_b0,
    u16* S16, u16* XT16) {
    int gi0 = blockIdx.x * 16;
    int b = gi0 >> 11;
    int il0 = gi0 & (L_ - 1);
    int tid = threadIdx.x;
    __shared__ float rbf_lds[16][NR];
    __shared__ __align__(16) u16 hgeo[16][136];
    __shared__ __align__(16) u16 h_lds[16][136];
    {
        int row = tid >> 4, r = tid & 15;
        float s = 0.f;
#pragma unroll
        for (int p = 0; p < 4; p++)
            s += rbfp[(size_t)p * BLN + (size_t)(gi0 + row) * NR + r];
        rbf_lds[row][r] = s;
    }
    __syncthreads();
    for (int e = tid; e < 16 * D_; e += 256) {
        int row = e >> 7, d = e & 127;
        float s = rbf_b[d];
#pragma unroll
        for (int r = 0; r < NR; r++) s += rbf_lds[row][r] * rbf_w[r * D_ + d];
        hgeo[row][d] = f2bf(s);
    }
    __syncthreads();
    int w = tid >> 6, lane = tid & 63;
    int rowf = lane & 15, kg = lane >> 4;
    f32x4 z = {0.f, 0.f, 0.f, 0.f};
    f32x4 acc[2] = {z, z};
    int za = Z[gi0 + rowf];
    for (int ks = 0; ks < 8; ks++) {
        int k0 = ks * 32 + kg * 8;
        bf16x8 a;
        if (k0 < 128) a = ld_bf8(atom16 + za * D_ + k0);
        else a = ld_bf8(&hgeo[rowf][k0 - 128]);
#pragma unroll
        for (int q = 0; q < 2; q++) {
            int cl = (w * 2 + q) * 16 + rowf;
            bf16x8 bb = ld_bf8(outwT + cl * (2 * D_) + k0);
            acc[q] = __builtin_amdgcn_mfma_f32_16x16x32_bf16(a, bb, acc[q], 0, 0, 0);
        }
    }
#pragma unroll
    for (int q = 0; q < 2; q++) {
        int cl = (w * 2 + q) * 16 + rowf;
        float bias = out_b[cl];
#pragma unroll
        for (int r = 0; r < 4; r++) h_lds[kg * 4 + r][cl] = f2bf(acc[q][r] + bias);
    }
    __syncthreads();
    f32x4 acc3[4] = {z, z, z, z};
    for (int ks = 0; ks < 4; ks++) {
        int k0 = ks * 32 + kg * 8;
        bf16x8 a = ld_bf8(&h_lds[rowf][k0]);
#pragma unroll
        for (int q = 0; q < 4; q++) {
            int nb = w * 4 + q;
            const u16* wp = (nb < 8) ? (selfT0 + (nb * 16 + rowf) * D_ + k0)
                                     : (msgT0 + ((nb - 8) * 16 + rowf) * D_ + k0);
            acc3[q] = __builtin_amdgcn_mfma_f32_16x16x32_bf16(a, ld_bf8(wp), acc3[q], 0, 0, 0);
        }
    }
#pragma unroll
    for (int q = 0; q < 4; q++) {
        int nb = w * 4 + q;
        if (nb < 8) {
            int cl = nb * 16 + rowf;
            float bias = self_b0[cl];
#pragma unroll
            for (int r = 0; r < 4; r++)
                S16[(size_t)(gi0 + kg * 4 + r) * D_ + cl] = f2bf(acc3[q][r] + bias);
        } else {
            int cl = (nb - 8) * 16 + rowf;
            float bias = msg_b0[cl];
            u16x4 pk;
#pragma unroll
            for (int r = 0; r < 4; r++) pk[r] = f2bf(acc3[q][r] + bias);
            int jj = il0 + kg * 4;
            *(u16x4*)(XT16 + (size_t)b * XTN + (jj >> 5) * (32 * D_) + cl * 32 + (jj & 31)) = pk;
        }
    }
}

// ---------------- mp_fused: pure MFMA msg GEMM (Wf A-frags) + epilogue + next S/X ----------------
__global__ __launch_bounds__(512, 2) void mp_fused_kernel(
    const u16* Wf, const u16* XT_in, const u16* S_in,
    const u16* updT_k, const float* upd_b_k,
    const u16* selfTn, const u16* msgTn, const float* self_bn, const float* msg_bn,
    u16* S_out, u16* XT_out, float* out_f32, int last) {
    int rt = blockIdx.x;
    int gi0 = rt * 16;
    int b = gi0 >> 11;
    int il0 = gi0 & (L_ - 1);
    int tid = threadIdx.x;
    int w = tid >> 6, lane = tid & 63;
    int rowf = lane & 15, kg = lane >> 4;

    __shared__ __align__(16) float red[4][16][128];  // 32 KB
    u16* msg_lds = (u16*)&red[0][0][0];              // [16][136] bf16 alias
    u16* h_lds = (u16*)&red[1][0][0];                // [16][136] bf16 alias

    f32x4 z = {0.f, 0.f, 0.f, 0.f};
    f32x4 acc[8] = {z, z, z, z, z, z, z, z};
    const u16* abase = Wf + (size_t)rt * (64 * 512) + (w * 8) * 512 + rowf * 32 + kg * 8;
    const u16* xbase = XT_in + (size_t)b * XTN + (w * 8) * (32 * D_) + rowf * 32 + kg * 8;
#pragma unroll
    for (int s = 0; s < 8; s++) {
        bf16x8 a = ld_bf8(abase + s * 512);
#pragma unroll
        for (int n = 0; n < 8; n++) {
            bf16x8 bb = ld_bf8(xbase + s * (32 * D_) + n * 512);
            acc[n] = __builtin_amdgcn_mfma_f32_16x16x32_bf16(a, bb, acc[n], 0, 0, 0);
        }
    }
    // ---- LDS tree reduce across 8 waves ----
    auto stash = [&](int slot) {
#pragma unroll
        for (int n = 0; n < 8; n++)
#pragma unroll
            for (int r = 0; r < 4; r++) {
                int row = kg * 4 + r, col = n * 16 + rowf;
                red[slot][row][(col + 4 * row) & 127] = acc[n][r];
            }
    };
    auto grab = [&](int slot) {
#pragma unroll
        for (int n = 0; n < 8; n++)
#pragma unroll
            for (int r = 0; r < 4; r++) {
                int row = kg * 4 + r, col = n * 16 + rowf;
                acc[n][r] += red[slot][row][(col + 4 * row) & 127];
            }
    };
    if (w >= 4) stash(w - 4);
    __syncthreads();
    if (w < 4) grab(w);
    if (w == 2 || w == 3) stash(w);
    __syncthreads();
    if (w < 2) grab(w + 2);
    if (w == 1) stash(3);
    __syncthreads();
    if (w == 0) {
        grab(3);
#pragma unroll
        for (int n = 0; n < 8; n++)
#pragma unroll
            for (int r = 0; r < 4; r++)
                msg_lds[(kg * 4 + r) * 136 + n * 16 + rowf] = f2bf(acc[n][r]);
    }
    __syncthreads();
    // ---- epilogue: h' = S@U_top + msg@U_bot + bias ----
    f32x4 acc2 = z;
    int cl = w * 16 + rowf;
#pragma unroll
    for (int ks = 0; ks < 8; ks++) {
        int k0 = ks * 32 + kg * 8;
        bf16x8 av = (ks < 4) ? ld_bf8(S_in + (size_t)(gi0 + rowf) * D_ + k0)
                             : ld_bf8(msg_lds + rowf * 136 + (k0 - 128));
        acc2 = __builtin_amdgcn_mfma_f32_16x16x32_bf16(
            av, ld_bf8(updT_k + cl * 2 * D_ + k0), acc2, 0, 0, 0);
    }
    float bias = upd_b_k[cl];
    if (last) {
#pragma unroll
        for (int r = 0; r < 4; r++)
            out_f32[(size_t)(gi0 + kg * 4 + r) * D_ + cl] = acc2[r] + bias;
        return;
    }
#pragma unroll
    for (int r = 0; r < 4; r++)
        h_lds[(kg * 4 + r) * 136 + cl] = f2bf(acc2[r] + bias);
    __syncthreads();
    // ---- next-layer S/X (row-local) ----
    f32x4 a30 = z, a31 = z;
#pragma unroll
    for (int ks = 0; ks < 4; ks++) {
        int k0 = ks * 32 + kg * 8;
        bf16x8 av = ld_bf8(h_lds + rowf * 136 + k0);
        a30 = __builtin_amdgcn_mfma_f32_16x16x32_bf16(
            av, ld_bf8(selfTn + cl * D_ + k0), a30, 0, 0, 0);
        a31 = __builtin_amdgcn_mfma_f32_16x16x32_bf16(
            av, ld_bf8(msgTn + cl * D_ + k0), a31, 0, 0, 0);
    }
    float bs = self_bn[cl], bm = msg_bn[cl];
#pragma unroll
    for (int r = 0; r < 4; r++)
        S_out[(size_t)(gi0 + kg * 4 + r) * D_ + cl] = f2bf(a30[r] + bs);
    u16x4 pk;
#pragma unroll
    for (int r = 0; r < 4; r++) pk[r] = f2bf(a31[r] + bm);
    int jj = il0 + kg * 4;
    *(u16x4*)(XT_out + (size_t)b * XTN + (jj >> 5) * (32 * D_) + cl * 32 + (jj & 31)) = pk;
}

extern "C" void kernel_launch(void* const* d_in, const int* in_sizes, int n_in,
                              void* d_out, int out_size, void* d_ws, size_t ws_size,
                              hipStream_t stream) {
    const float* coords = (const float*)d_in[0];
    const int* Z = (const int*)d_in[1];
    const float* atom_emb = (const float*)d_in[2];
    const float* gamma = (const float*)d_in[3];
    const float* centers = (const float*)d_in[4];
    const float* rbf_w = (const float*)d_in[5];
    const float* rbf_b = (const float*)d_in[6];
    const float* out_w = (const float*)d_in[7];
    const float* out_b = (const float*)d_in[8];
    const float* self_w = (const float*)d_in[9];
    const float* self_b = (const float*)d_in[10];
    const float* msg_w = (const float*)d_in[11];
    const float* msg_b = (const float*)d_in[12];
    const float* upd_w = (const float*)d_in[13];
    const float* upd_b = (const float*)d_in[14];
    float* out = (float*)d_out;

    char* ws = (char*)d_ws;
    u16* Wf = (u16*)(ws + 0);               // 16,777,216
    u16* S_a = (u16*)(ws + 16777216);       // 1,048,576
    u16* S_b = (u16*)(ws + 17825792);       // 1,048,576
    u16* XT_a = (u16*)(ws + 18874368);      // 1,048,576
    u16* XT_b = (u16*)(ws + 19922944);      // 1,048,576
    float* rbfp = (float*)(ws + 20971520);  // 1,048,576 (4 partials)
    u16* atom16 = (u16*)(ws + 22020096);    // 32,768
    u16* outwT = (u16*)(ws + 22052864);     // 65,536
    u16* selfT = (u16*)(ws + 22118400);     // 98,304
    u16* msgT = (u16*)(ws + 22216704);      // 98,304
    u16* updT = (u16*)(ws + 22315008);      // 196,608

    prep_kernel<<<64, 256, 0, stream>>>(atom_emb, out_w, self_w, msg_w, upd_w,
                                        atom16, outwT, selfT, msgT, updT);
    pairw_kernel<<<(B_ * L_ / 16) * 4, 512, 0, stream>>>(coords, gamma, centers,
                                                         Wf, rbfp);
    enc_sx_kernel<<<(B_ * L_) / 16, 256, 0, stream>>>(
        Z, rbf_w, rbf_b, out_b, rbfp, atom16, outwT,
        selfT, msgT, self_b, msg_b, S_a, XT_a);
    // layer 0: a -> b
    mp_fused_kernel<<<256, 512, 0, stream>>>(
        Wf, XT_a, S_a, updT + 0 * 2 * DD, upd_b + 0 * D_,
        selfT + 1 * DD, msgT + 1 * DD, self_b + 1 * D_, msg_b + 1 * D_,
        S_b, XT_b, out, 0);
    // layer 1: b -> a
    mp_fused_kernel<<<256, 512, 0, stream>>>(
        Wf, XT_b, S_b, updT + 1 * 2 * DD, upd_b + 1 * D_,
        selfT + 2 * DD, msgT + 2 * DD, self_b + 2 * D_, msg_b + 2 * D_,
        S_a, XT_a, out, 0);
    // layer 2 (last): a -> out
    mp_fused_kernel<<<256, 512, 0, stream>>>(
        Wf, XT_a, S_a, updT + 2 * 2 * DD, upd_b + 2 * D_,
        selfT, msgT, self_b, msg_b, S_b, XT_b, out, 1);
}

// Round 7
// 109.093 us; speedup vs baseline: 1.1178x; 1.1178x over previous
//
#include <hip/hip_runtime.h>
#include <hip/hip_bf16.h>

typedef unsigned short u16;
typedef __bf16 bf16x8 __attribute__((ext_vector_type(8)));
typedef float f32x4 __attribute__((ext_vector_type(4)));
typedef u16 u16x4 __attribute__((ext_vector_type(4)));

#define B_ 2
#define L_ 2048
#define D_ 128
#define KLAY 3
#define NR 16
#define NATOM 118
#define DD (D_ * D_)
#define XTN (L_ * D_)
#define CHUNK 1024

static __device__ __forceinline__ u16 f2bf(float f) {
    union { float f; unsigned u; } v; v.f = f;
    unsigned r = v.u + 0x7FFFu + ((v.u >> 16) & 1u);
    return (u16)(r >> 16);
}
static __device__ __forceinline__ bf16x8 ld_bf8(const u16* p) {
    return *(const bf16x8*)p;
}

// ---------------- prep: weights -> bf16 [n][k] layouts ----------------
__global__ __launch_bounds__(256) void prep_kernel(
    const float* atom_emb, const float* out_w, const float* self_w,
    const float* msg_w, const float* upd_w,
    u16* atom16, u16* outwT, u16* selfT, u16* msgT, u16* updT) {
    const int T0 = NATOM * D_;
    const int T1 = D_ * 2 * D_;
    const int T2 = KLAY * DD;
    const int T3 = KLAY * DD;
    const int T4 = KLAY * 2 * DD;
    int total = T0 + T1 + T2 + T3 + T4;
    for (int t = blockIdx.x * blockDim.x + threadIdx.x; t < total;
         t += gridDim.x * blockDim.x) {
        int u = t;
        if (u < T0) { atom16[u] = f2bf(atom_emb[u]); continue; }
        u -= T0;
        if (u < T1) {
            int n = u / (2 * D_), k = u % (2 * D_);
            outwT[u] = f2bf(out_w[k * D_ + n]);
            continue;
        }
        u -= T1;
        if (u < T2) {
            int kk = u / DD, v = u % DD;
            int n = v / D_, k = v % D_;
            selfT[u] = f2bf(self_w[kk * DD + k * D_ + n]);
            continue;
        }
        u -= T2;
        if (u < T3) {
            int kk = u / DD, v = u % DD;
            int n = v / D_, k = v % D_;
            msgT[u] = f2bf(msg_w[kk * DD + k * D_ + n]);
            continue;
        }
        u -= T3;
        {
            int kk = u / (2 * DD), v = u % (2 * DD);
            int n = v / (2 * D_), k = v % (2 * D_);
            updT[u] = f2bf(upd_w[kk * 2 * DD + k * D_ + n]);
        }
    }
}

// ---------------- rbf: rbf_local via grouped-exp identity (9 trans/pair) ----------------
__global__ __launch_bounds__(256) void rbf_kernel(
    const float* coords, const float* gamma_p, const float* centers,
    float* rbf_loc) {
    int w = threadIdx.x >> 6, lane = threadIdx.x & 63;
    int bi = blockIdx.x * 4 + w;
    int b = bi >> 11;
    float gamma = gamma_p[0];
    float dl = centers[1] - centers[0];
    float c4[4];
#pragma unroll
    for (int g = 0; g < 4; g++) c4[g] = centers[4 * g];
    float two_gdl = 2.f * gamma * dl;
    float cx = coords[bi * 3 + 0];
    float cy = coords[bi * 3 + 1];
    float cz = coords[bi * 3 + 2];
    const float* cb = coords + (size_t)b * L_ * 3;
    float acc[4][4];
#pragma unroll
    for (int g = 0; g < 4; g++)
#pragma unroll
        for (int m = 0; m < 4; m++) acc[g][m] = 0.f;
    for (int it = 0; it < L_ / 64; it++) {
        int j = lane + 64 * it;
        float dx = cx - cb[j * 3 + 0];
        float dy = cy - cb[j * 3 + 1];
        float dz = cz - cb[j * 3 + 2];
        float sq = dx * dx + dy * dy + dz * dz;
        float d = sq > 0.f ? sqrtf(sq) : 0.f;
#pragma unroll
        for (int g = 0; g < 4; g++) {
            float x = d - c4[g];
            float base = __expf(-gamma * x * x);
            float u = __expf(fminf(two_gdl * x, 29.f));
            float p = base;
            acc[g][0] += p;
            p *= u; acc[g][1] += p;
            p *= u; acc[g][2] += p;
            p *= u; acc[g][3] += p;
        }
    }
#pragma unroll
    for (int off = 32; off > 0; off >>= 1)
#pragma unroll
        for (int g = 0; g < 4; g++)
#pragma unroll
            for (int m = 0; m < 4; m++) acc[g][m] += __shfl_xor(acc[g][m], off);
    if (lane == 0) {
#pragma unroll
        for (int m = 0; m < 4; m++) {
            float Km = __expf(-gamma * (m * dl) * (m * dl)) * (1.0f / L_);
#pragma unroll
            for (int g = 0; g < 4; g++)
                rbf_loc[(size_t)bi * NR + 4 * g + m] = acc[g][m] * Km;
        }
    }
}

// ---------------- enc_sx: encoder + layer-0 S/X (row-local) ----------------
__global__ __launch_bounds__(256) void enc_sx_kernel(
    const int* Z, const float* rbf_w, const float* rbf_b, const float* out_b,
    const float* rbf_loc, const u16* atom16, const u16* outwT,
    const u16* selfT0, const u16* msgT0, const float* self_b0, const float* msg_b0,
    u16* S16, u16* XT16) {
    int gi0 = blockIdx.x * 16;
    int b = gi0 >> 11;
    int il0 = gi0 & (L_ - 1);
    int tid = threadIdx.x;
    __shared__ __align__(16) u16 hgeo[16][136];
    __shared__ __align__(16) u16 h_lds[16][136];
    for (int e = tid; e < 16 * D_; e += 256) {
        int row = e >> 7, d = e & 127;
        int gi = gi0 + row;
        float s = rbf_b[d];
#pragma unroll
        for (int r = 0; r < NR; r++)
            s += rbf_loc[(size_t)gi * NR + r] * rbf_w[r * D_ + d];
        hgeo[row][d] = f2bf(s);
    }
    __syncthreads();
    int w = tid >> 6, lane = tid & 63;
    int rowf = lane & 15, kg = lane >> 4;
    f32x4 z = {0.f, 0.f, 0.f, 0.f};
    f32x4 acc[2] = {z, z};
    int za = Z[gi0 + rowf];
    for (int ks = 0; ks < 8; ks++) {
        int k0 = ks * 32 + kg * 8;
        bf16x8 a;
        if (k0 < 128) a = ld_bf8(atom16 + za * D_ + k0);
        else a = ld_bf8(&hgeo[rowf][k0 - 128]);
#pragma unroll
        for (int q = 0; q < 2; q++) {
            int cl = (w * 2 + q) * 16 + rowf;
            bf16x8 bb = ld_bf8(outwT + cl * (2 * D_) + k0);
            acc[q] = __builtin_amdgcn_mfma_f32_16x16x32_bf16(a, bb, acc[q], 0, 0, 0);
        }
    }
#pragma unroll
    for (int q = 0; q < 2; q++) {
        int cl = (w * 2 + q) * 16 + rowf;
        float bias = out_b[cl];
#pragma unroll
        for (int r = 0; r < 4; r++) h_lds[kg * 4 + r][cl] = f2bf(acc[q][r] + bias);
    }
    __syncthreads();
    f32x4 acc3[4] = {z, z, z, z};
    for (int ks = 0; ks < 4; ks++) {
        int k0 = ks * 32 + kg * 8;
        bf16x8 a = ld_bf8(&h_lds[rowf][k0]);
#pragma unroll
        for (int q = 0; q < 4; q++) {
            int nb = w * 4 + q;
            const u16* wp = (nb < 8) ? (selfT0 + (nb * 16 + rowf) * D_ + k0)
                                     : (msgT0 + ((nb - 8) * 16 + rowf) * D_ + k0);
            acc3[q] = __builtin_amdgcn_mfma_f32_16x16x32_bf16(a, ld_bf8(wp), acc3[q], 0, 0, 0);
        }
    }
#pragma unroll
    for (int q = 0; q < 4; q++) {
        int nb = w * 4 + q;
        if (nb < 8) {
            int cl = nb * 16 + rowf;
            float bias = self_b0[cl];
#pragma unroll
            for (int r = 0; r < 4; r++)
                S16[(size_t)(gi0 + kg * 4 + r) * D_ + cl] = f2bf(acc3[q][r] + bias);
        } else {
            int cl = (nb - 8) * 16 + rowf;
            float bias = msg_b0[cl];
            u16x4 pk;
#pragma unroll
            for (int r = 0; r < 4; r++) pk[r] = f2bf(acc3[q][r] + bias);
            int jj = il0 + kg * 4;
            *(u16x4*)(XT16 + (size_t)b * XTN + (jj >> 5) * (32 * D_) + cl * 32 + (jj & 31)) = pk;
        }
    }
}

// ---------------- mp_fused: 16 waves; W cooperatively gen'd into LDS (A-frag layout);
//                  wave (nb, jh) = pure MFMA over its n-block/j-half; 1-stage pair reduce ----------------
__global__ __launch_bounds__(1024, 4) void mp_fused_kernel(
    const float* coords, const u16* XT_in, const u16* S_in,
    const u16* updT_k, const float* upd_b_k,
    const u16* selfTn, const u16* msgTn, const float* self_bn, const float* msg_bn,
    u16* S_out, u16* XT_out, float* out_f32, int last) {
    int rt = blockIdx.x;
    int gi0 = rt * 16;
    int b = gi0 >> 11;
    int il0 = gi0 & (L_ - 1);
    int tid = threadIdx.x;
    int w = tid >> 6, lane = tid & 63;
    int rowf = lane & 15, kg = lane >> 4;

    __shared__ float cj[CHUNK * 3];                      // 12 KB
    __shared__ __align__(16) u16 Wlds[32][4][16][8];     // 32 KB  [slice][kg][row][e]
    __shared__ float red[8][16][20];                     // 10 KB  pair-reduce
    __shared__ __align__(16) u16 msg_lds[16][136];       // 4.25 KB
    __shared__ __align__(16) u16 h_lds[16][136];         // 4.25 KB  (total 64,000 B)

    // W-gen thread mapping: row = tid&15, jg = tid>>4 (64 j-groups of 8)
    int grow = tid & 15, jg = tid >> 4;
    float rx = coords[(gi0 + grow) * 3 + 0];
    float ry = coords[(gi0 + grow) * 3 + 1];
    float rz = coords[(gi0 + grow) * 3 + 2];

    // MFMA role: wave w -> n-block nb, j-half jh
    int nb = w & 7, jh = w >> 3;
    f32x4 z = {0.f, 0.f, 0.f, 0.f};
    f32x4 acc = z;

    for (int c = 0; c < 2; c++) {
        // ---- stage this chunk's coords ----
        if (tid < CHUNK * 3 / 4) {
            ((float4*)cj)[tid] =
                ((const float4*)(coords + ((size_t)b * L_ + c * CHUNK) * 3))[tid];
        }
        __syncthreads();
        // ---- W-gen into Wlds (each thread: 2 groups of 8 consecutive j) ----
#pragma unroll
        for (int it = 0; it < 2; it++) {
            int j0 = it * 512 + jg * 8;  // local j within chunk
            union { bf16x8 v; u16 e[8]; } pk;
#pragma unroll
            for (int e = 0; e < 8; e++) {
                int jl = j0 + e;
                float dx = rx - cj[jl * 3 + 0];
                float dy = ry - cj[jl * 3 + 1];
                float dz = rz - cj[jl * 3 + 2];
                float sq = dx * dx + dy * dy + dz * dz;
                float d = sqrtf(sq);
                pk.e[e] = f2bf(__expf(-d));
            }
            *(bf16x8*)&Wlds[j0 >> 5][(j0 & 31) >> 3][grow][0] = pk.v;
        }
        __syncthreads();
        // ---- MFMA: 16 slices for this wave's (nb, jh) ----
        const u16* xb = XT_in + (size_t)b * XTN + (c * 32 + jh * 16) * (32 * D_) +
                        (nb * 16 + rowf) * 32 + kg * 8;
#pragma unroll
        for (int si = 0; si < 16; si++) {
            bf16x8 a = *(const bf16x8*)&Wlds[jh * 16 + si][kg][rowf][0];
            bf16x8 bb = ld_bf8(xb + si * (32 * D_));
            acc = __builtin_amdgcn_mfma_f32_16x16x32_bf16(a, bb, acc, 0, 0, 0);
        }
        __syncthreads();  // Wlds/cj safe to overwrite
    }
    // ---- pair reduce: jh=1 stashes, jh=0 adds; msg -> msg_lds bf16 ----
    if (jh == 1) {
#pragma unroll
        for (int r = 0; r < 4; r++) red[nb][kg * 4 + r][rowf] = acc[r];
    }
    __syncthreads();
    if (jh == 0) {
#pragma unroll
        for (int r = 0; r < 4; r++) {
            float m = acc[r] + red[nb][kg * 4 + r][rowf];
            msg_lds[kg * 4 + r][nb * 16 + rowf] = f2bf(m);
        }
    }
    __syncthreads();
    // ---- epilogue: h' = S@U_top + msg@U_bot + bias (waves 0-7) ----
    if (w < 8) {
        f32x4 acc2 = z;
        int cl = w * 16 + rowf;
#pragma unroll
        for (int ks = 0; ks < 8; ks++) {
            int k0 = ks * 32 + kg * 8;
            bf16x8 av = (ks < 4) ? ld_bf8(S_in + (size_t)(gi0 + rowf) * D_ + k0)
                                 : ld_bf8(&msg_lds[rowf][k0 - 128]);
            acc2 = __builtin_amdgcn_mfma_f32_16x16x32_bf16(
                av, ld_bf8(updT_k + cl * 2 * D_ + k0), acc2, 0, 0, 0);
        }
        float bias = upd_b_k[cl];
        if (last) {
#pragma unroll
            for (int r = 0; r < 4; r++)
                out_f32[(size_t)(gi0 + kg * 4 + r) * D_ + cl] = acc2[r] + bias;
        } else {
#pragma unroll
            for (int r = 0; r < 4; r++)
                h_lds[kg * 4 + r][cl] = f2bf(acc2[r] + bias);
        }
    }
    if (last) return;
    __syncthreads();
    // ---- next-layer S (waves 0-7) / X^T (waves 8-15), row-local ----
    {
        int cl = nb * 16 + rowf;
        const u16* wT = (w < 8) ? (selfTn + cl * D_) : (msgTn + cl * D_);
        f32x4 a3 = z;
#pragma unroll
        for (int ks = 0; ks < 4; ks++) {
            int k0 = ks * 32 + kg * 8;
            a3 = __builtin_amdgcn_mfma_f32_16x16x32_bf16(
                ld_bf8(&h_lds[rowf][k0]), ld_bf8(wT + k0), a3, 0, 0, 0);
        }
        if (w < 8) {
            float bias = self_bn[cl];
#pragma unroll
            for (int r = 0; r < 4; r++)
                S_out[(size_t)(gi0 + kg * 4 + r) * D_ + cl] = f2bf(a3[r] + bias);
        } else {
            float bias = msg_bn[cl];
            u16x4 pk;
#pragma unroll
            for (int r = 0; r < 4; r++) pk[r] = f2bf(a3[r] + bias);
            int jj = il0 + kg * 4;
            *(u16x4*)(XT_out + (size_t)b * XTN + (jj >> 5) * (32 * D_) + cl * 32 + (jj & 31)) = pk;
        }
    }
}

extern "C" void kernel_launch(void* const* d_in, const int* in_sizes, int n_in,
                              void* d_out, int out_size, void* d_ws, size_t ws_size,
                              hipStream_t stream) {
    const float* coords = (const float*)d_in[0];
    const int* Z = (const int*)d_in[1];
    const float* atom_emb = (const float*)d_in[2];
    const float* gamma = (const float*)d_in[3];
    const float* centers = (const float*)d_in[4];
    const float* rbf_w = (const float*)d_in[5];
    const float* rbf_b = (const float*)d_in[6];
    const float* out_w = (const float*)d_in[7];
    const float* out_b = (const float*)d_in[8];
    const float* self_w = (const float*)d_in[9];
    const float* self_b = (const float*)d_in[10];
    const float* msg_w = (const float*)d_in[11];
    const float* msg_b = (const float*)d_in[12];
    const float* upd_w = (const float*)d_in[13];
    const float* upd_b = (const float*)d_in[14];
    float* out = (float*)d_out;

    char* ws = (char*)d_ws;
    u16* S_a = (u16*)(ws + 0);              // 1,048,576
    u16* S_b = (u16*)(ws + 1048576);        // 1,048,576
    u16* XT_a = (u16*)(ws + 2097152);       // 1,048,576
    u16* XT_b = (u16*)(ws + 3145728);       // 1,048,576
    float* rbfl = (float*)(ws + 4194304);   // 262,144
    u16* atom16 = (u16*)(ws + 4456448);     // 32,768
    u16* outwT = (u16*)(ws + 4489216);      // 65,536
    u16* selfT = (u16*)(ws + 4554752);      // 98,304
    u16* msgT = (u16*)(ws + 4653056);       // 98,304
    u16* updT = (u16*)(ws + 4751360);       // 196,608

    prep_kernel<<<64, 256, 0, stream>>>(atom_emb, out_w, self_w, msg_w, upd_w,
                                        atom16, outwT, selfT, msgT, updT);
    rbf_kernel<<<(B_ * L_) / 4, 256, 0, stream>>>(coords, gamma, centers, rbfl);
    enc_sx_kernel<<<(B_ * L_) / 16, 256, 0, stream>>>(
        Z, rbf_w, rbf_b, out_b, rbfl, atom16, outwT,
        selfT, msgT, self_b, msg_b, S_a, XT_a);
    // layer 0: a -> b
    mp_fused_kernel<<<256, 1024, 0, stream>>>(
        coords, XT_a, S_a, updT + 0 * 2 * DD, upd_b + 0 * D_,
        selfT + 1 * DD, msgT + 1 * DD, self_b + 1 * D_, msg_b + 1 * D_,
        S_b, XT_b, out, 0);
    // layer 1: b -> a
    mp_fused_kernel<<<256, 1024, 0, stream>>>(
        coords, XT_b, S_b, updT + 1 * 2 * DD, upd_b + 1 * D_,
        selfT + 2 * DD, msgT + 2 * DD, self_b + 2 * D_, msg_b + 2 * D_,
        S_a, XT_a, out, 0);
    // layer 2 (last): a -> out
    mp_fused_kernel<<<256, 1024, 0, stream>>>(
        coords, XT_a, S_a, updT + 2 * 2 * DD, upd_b + 2 * D_,
        selfT, msgT, self_b, msg_b, S_b, XT_b, out, 1);
}